// Round 1
// baseline (368.322 us; speedup 1.0000x reference)
//
#include <hip/hip_runtime.h>

// RegressionWisard predict (centrality='mean')
//   input:  [B=4096, E=8192] int32 bits
//   map:    [E] permutation (int32 per harness integer convention)
//   counts: [N=512, 65536] int32
//   sums:   [N=512, 65536] float32
//   out:    [B] float32 = nan_to_num(sum(s where c>0) / sum(c where c>0))

constexpr int BATCH   = 4096;
constexpr int ENTRY   = 8192;
constexpr int TUP     = 16;
constexpr int NEUR    = ENTRY / TUP;   // 512
constexpr int THREADS = 256;

__global__ __launch_bounds__(THREADS) void wisard_kernel(
    const int*   __restrict__ input,
    const int*   __restrict__ mapping,
    const int*   __restrict__ counts,
    const float* __restrict__ sums,
    float*       __restrict__ out)
{
    // Bit-packed copy of this sample's input row: 8192 bits = 256 words = 1 KB
    __shared__ unsigned int packed[ENTRY / 32];
    __shared__ float s_resp[THREADS / 64];
    __shared__ int   s_cnt [THREADS / 64];

    const int b    = blockIdx.x;
    const int tid  = threadIdx.x;
    const int lane = tid & 63;
    const int wv   = tid >> 6;

    // --- Stage 1: coalesced load + ballot pack ---
    // Wave handles 64 consecutive elements per iteration: one wave64 dword
    // load (256 B transaction) -> one 64-bit ballot -> 2 packed LDS words.
    const int* row = input + (size_t)b * ENTRY;
    #pragma unroll
    for (int i = wv; i < ENTRY / 64; i += THREADS / 64) {   // 32 iters/wave
        const int j = i * 64 + lane;
        const unsigned long long m = __ballot(row[j] & 1);
        if (lane == 0) {
            packed[i * 2]     = (unsigned int)(m);
            packed[i * 2 + 1] = (unsigned int)(m >> 32);
        }
    }
    __syncthreads();

    // --- Stage 2: per-neuron address build + table gather ---
    float resp = 0.0f;
    int   cnt  = 0;
    #pragma unroll
    for (int k = 0; k < NEUR / THREADS; ++k) {              // 2 neurons/thread
        const int n = tid + k * THREADS;
        const int* map_n = mapping + n * TUP;
        int addr = 0;
        #pragma unroll
        for (int t = 0; t < TUP; ++t) {
            // reference: addr bit (T-1-t) = bit t of the tuple -> t=0 is MSB
            const int j = map_n[t];
            const int bit = (packed[j >> 5] >> (j & 31)) & 1;
            addr = (addr << 1) | bit;
        }
        const int idx = (n << 16) | addr;
        const int c = counts[idx];
        if (c > 0) {
            resp += sums[idx];
            cnt  += c;
        }
    }

    // --- Stage 3: block reduction ---
    #pragma unroll
    for (int off = 32; off > 0; off >>= 1) {
        resp += __shfl_down(resp, off, 64);
        cnt  += __shfl_down(cnt,  off, 64);
    }
    if (lane == 0) { s_resp[wv] = resp; s_cnt[wv] = cnt; }
    __syncthreads();
    if (tid == 0) {
        float r = s_resp[0] + s_resp[1] + s_resp[2] + s_resp[3];
        int   c = s_cnt[0]  + s_cnt[1]  + s_cnt[2]  + s_cnt[3];
        out[b] = (c > 0) ? (r / (float)c) : 0.0f;   // nan_to_num(0/0) == 0
    }
}

extern "C" void kernel_launch(void* const* d_in, const int* in_sizes, int n_in,
                              void* d_out, int out_size, void* d_ws, size_t ws_size,
                              hipStream_t stream) {
    (void)in_sizes; (void)n_in; (void)out_size; (void)d_ws; (void)ws_size;
    const int*   input   = (const int*)d_in[0];
    const int*   mapping = (const int*)d_in[1];
    const int*   counts  = (const int*)d_in[2];
    const float* sums    = (const float*)d_in[3];
    float*       out     = (float*)d_out;

    wisard_kernel<<<BATCH, THREADS, 0, stream>>>(input, mapping, counts, sums, out);
}

// Round 2
// 367.882 us; speedup vs baseline: 1.0012x; 1.0012x over previous
//
#include <hip/hip_runtime.h>

// RegressionWisard predict (centrality='mean')
//   input:  [B=4096, E=8192] int32 bits
//   map:    [E] permutation int32
//   counts: [N=512, 65536] int32
//   sums:   [N=512, 65536] float32
//   out:    [B] float32 = nan_to_num(sum(s where c>0) / sum(c where c>0))
//
// R2: latency-bound on random gathers (R1: 2 TB/s @ 25% peak, VALUBusy 7.6%,
// traffic already at floor). Fixes: (1) unconditional c+s loads (remove the
// counts->sums dependency), (2) 2 samples/block -> 8 independent gathers per
// thread, (3) nontemporal input loads to keep tables resident in L3.

constexpr int BATCH   = 4096;
constexpr int ENTRY   = 8192;
constexpr int TUP     = 16;
constexpr int NEUR    = ENTRY / TUP;   // 512
constexpr int THREADS = 256;
constexpr int SPB     = 2;             // samples per block

__global__ __launch_bounds__(THREADS) void wisard_kernel(
    const int*   __restrict__ input,
    const int*   __restrict__ mapping,
    const int*   __restrict__ counts,
    const float* __restrict__ sums,
    float*       __restrict__ out)
{
    // Bit-packed input rows: SPB * 256 words = 2 KB
    __shared__ unsigned int packed[SPB][ENTRY / 32];
    __shared__ float s_resp[SPB][THREADS / 64];
    __shared__ int   s_cnt [SPB][THREADS / 64];

    const int tid  = threadIdx.x;
    const int lane = tid & 63;
    const int wv   = tid >> 6;
    const int b0   = blockIdx.x * SPB;

    // --- Stage 1: coalesced nontemporal load + ballot pack (both samples) ---
    #pragma unroll
    for (int s = 0; s < SPB; ++s) {
        const int* row = input + (size_t)(b0 + s) * ENTRY;
        #pragma unroll
        for (int i = wv; i < ENTRY / 64; i += THREADS / 64) {   // 32 iters/wave
            const int v = __builtin_nontemporal_load(&row[i * 64 + lane]);
            const unsigned long long m = __ballot(v & 1);
            if (lane == 0) {
                packed[s][i * 2]     = (unsigned int)(m);
                packed[s][i * 2 + 1] = (unsigned int)(m >> 32);
            }
        }
    }
    __syncthreads();

    // --- Stage 2: build all 4 addresses, then issue all 8 gathers ---
    int idx[SPB][2];
    #pragma unroll
    for (int k = 0; k < 2; ++k) {                 // 2 neurons/thread
        const int n = tid + k * THREADS;
        const int* map_n = mapping + n * TUP;
        int addr[SPB] = {0, 0};
        #pragma unroll
        for (int t = 0; t < TUP; ++t) {
            const int j = map_n[t];               // shared across samples
            const unsigned w = j >> 5, sh = j & 31;
            #pragma unroll
            for (int s = 0; s < SPB; ++s) {
                const int bit = (packed[s][w] >> sh) & 1;
                addr[s] = (addr[s] << 1) | bit;
            }
        }
        #pragma unroll
        for (int s = 0; s < SPB; ++s) idx[s][k] = (n << 16) | addr[s];
    }

    // 8 independent loads — no control-flow dependency between c and s.
    int   cv[SPB][2];
    float sv[SPB][2];
    #pragma unroll
    for (int s = 0; s < SPB; ++s)
        #pragma unroll
        for (int k = 0; k < 2; ++k) {
            cv[s][k] = counts[idx[s][k]];
            sv[s][k] = sums  [idx[s][k]];
        }

    float resp[SPB];
    int   cnt [SPB];
    #pragma unroll
    for (int s = 0; s < SPB; ++s) {
        resp[s] = 0.0f; cnt[s] = 0;
        #pragma unroll
        for (int k = 0; k < 2; ++k) {
            const bool t = cv[s][k] > 0;
            resp[s] += t ? sv[s][k] : 0.0f;
            cnt [s] += t ? cv[s][k] : 0;
        }
    }

    // --- Stage 3: block reduction per sample ---
    #pragma unroll
    for (int s = 0; s < SPB; ++s) {
        float r = resp[s]; int c = cnt[s];
        #pragma unroll
        for (int off = 32; off > 0; off >>= 1) {
            r += __shfl_down(r, off, 64);
            c += __shfl_down(c, off, 64);
        }
        if (lane == 0) { s_resp[s][wv] = r; s_cnt[s][wv] = c; }
    }
    __syncthreads();
    if (tid < SPB) {
        float r = 0.0f; int c = 0;
        #pragma unroll
        for (int w = 0; w < THREADS / 64; ++w) { r += s_resp[tid][w]; c += s_cnt[tid][w]; }
        out[b0 + tid] = (c > 0) ? (r / (float)c) : 0.0f;   // nan_to_num(0/0)==0
    }
}

extern "C" void kernel_launch(void* const* d_in, const int* in_sizes, int n_in,
                              void* d_out, int out_size, void* d_ws, size_t ws_size,
                              hipStream_t stream) {
    (void)in_sizes; (void)n_in; (void)out_size; (void)d_ws; (void)ws_size;
    const int*   input   = (const int*)d_in[0];
    const int*   mapping = (const int*)d_in[1];
    const int*   counts  = (const int*)d_in[2];
    const float* sums    = (const float*)d_in[3];
    float*       out     = (float*)d_out;

    wisard_kernel<<<BATCH / SPB, THREADS, 0, stream>>>(input, mapping, counts, sums, out);
}